// Round 6
// baseline (402.087 us; speedup 1.0000x reference)
//
#include <hip/hip_runtime.h>
#include <math.h>

#define HID 1024
#define NROWS 2048

typedef __attribute__((ext_vector_type(8))) short short8;
typedef __attribute__((ext_vector_type(4))) short short4_t;
typedef __attribute__((ext_vector_type(4))) float f32x4;

__device__ __forceinline__ short f2bf(float f) {
  union { float f; unsigned u; } v; v.f = f;
  unsigned r = v.u + 0x7fffu + ((v.u >> 16) & 1u);
  return (short)(r >> 16);
}
__device__ __forceinline__ float bf2f(short s) {
  union { unsigned u; float f; } v; v.u = ((unsigned)(unsigned short)s) << 16;
  return v.f;
}
__device__ __forceinline__ float wave_sum(float a) {
#pragma unroll
  for (int off = 32; off; off >>= 1) a += __shfl_xor(a, off, 64);
  return a;
}

// ---------------------------------------------------------------------------
// PREP: block 0 = classify; blocks 1..512 = x fp32->bf16 (16 elem/thread);
// blocks 513.. = 64x64 transposes (fp32 [K,N] -> bf16 [Npad,K]).
// Transpose blocks: 256+64+32+2560+1888+816 = 5616.  Grid = 6129.
// ---------------------------------------------------------------------------
__global__ __launch_bounds__(256) void prep(
    const float* __restrict__ x, const int* __restrict__ y,
    const float* __restrict__ Wp0, const float* __restrict__ Wp1,
    const float* __restrict__ Wp2, const float* __restrict__ Wl0,
    const float* __restrict__ Wl1, const float* __restrict__ Wl2,
    short* __restrict__ xb,
    int* __restrict__ counts, int* __restrict__ slot_of_row,
    int* __restrict__ rows1, int* __restrict__ rows2,
    short* __restrict__ T0, short* __restrict__ T1, short* __restrict__ T2,
    short* __restrict__ T3, short* __restrict__ T4, short* __restrict__ T5) {
  const int tid = threadIdx.x;
  int b = blockIdx.x;
  if (b == 0) {                       // ---- classify ----
    __shared__ int c1s, c2s;
    if (tid == 0) { c1s = 0; c2s = 0; }
    __syncthreads();
    for (int r = tid; r < NROWS; r += 256) {
      const int yy = y[r];
      if (yy >= 20000) {
        const int s = atomicAdd(&c2s, 1);
        slot_of_row[r] = s; rows2[s] = r;
      } else if (yy >= 10000) {
        const int s = atomicAdd(&c1s, 1);
        slot_of_row[r] = s; rows1[s] = r;
      } else {
        slot_of_row[r] = -1;
      }
    }
    __syncthreads();
    if (tid == 0) { counts[0] = NROWS; counts[1] = c1s; counts[2] = c2s; }
    return;
  }
  if (b <= 512) {                     // ---- cvt x: 4 float4 rounds ----
    const int base = (b - 1) * 4096;
#pragma unroll
    for (int j = 0; j < 4; ++j) {
      const int i = base + j * 1024 + tid * 4;
      const float4 v = *(const float4*)&x[i];
      short4_t o;
      o.x = f2bf(v.x); o.y = f2bf(v.y); o.z = f2bf(v.z); o.w = f2bf(v.w);
      *(short4_t*)&xb[i] = o;
    }
    return;
  }
  b -= 513;                           // ---- 64x64 transposes ----
  const float* W; short* BT; int K, N, Npad, tn;
  if (b < 256)               { W = Wp0; BT = T0; K = 1024; N = 1024;  Npad = 1024;  tn = 16;  }
  else if ((b -= 256) < 64)  { W = Wp1; BT = T1; K = 1024; N = 256;   Npad = 256;   tn = 4;   }
  else if ((b -= 64) < 32)   { W = Wp2; BT = T2; K = 1024; N = 64;    Npad = 128;   tn = 2;   }
  else if ((b -= 32) < 2560) { W = Wl0; BT = T3; K = 1024; N = 10000; Npad = 10240; tn = 160; }
  else if ((b -= 2560) < 1888){W = Wl1; BT = T4; K = 256;  N = 30000; Npad = 30208; tn = 472; }
  else { b -= 1888;            W = Wl2; BT = T5; K = 64;   N = 52000; Npad = 52224; tn = 816; }

  __shared__ float T[64][65];
  const int n0 = (b % tn) * 64, k0 = (b / tn) * 64;
  const int rr = tid >> 4, cc = (tid & 15) * 4;
#pragma unroll
  for (int j = 0; j < 4; ++j) {
    const int kr = rr + j * 16;
    const float* p = &W[(size_t)(k0 + kr) * N + n0 + cc];
    float v0 = 0.f, v1 = 0.f, v2 = 0.f, v3 = 0.f;
    if (n0 + cc + 3 < N) {
      const float4 v = *(const float4*)p;
      v0 = v.x; v1 = v.y; v2 = v.z; v3 = v.w;
    } else {
      if (n0 + cc + 0 < N) v0 = p[0];
      if (n0 + cc + 1 < N) v1 = p[1];
      if (n0 + cc + 2 < N) v2 = p[2];
    }
    T[kr][cc] = v0; T[kr][cc + 1] = v1; T[kr][cc + 2] = v2; T[kr][cc + 3] = v3;
  }
  __syncthreads();
  const int nl = tid >> 2, ks = (tid & 3) * 16;
  const int n = n0 + nl;
  if (n < Npad) {
    const bool z = (n >= N);
    short* dst = &BT[(size_t)n * K + k0 + ks];
#pragma unroll
    for (int h = 0; h < 2; ++h) {
      short8 o;
#pragma unroll
      for (int e = 0; e < 8; ++e)
        o[e] = z ? (short)0 : f2bf(T[ks + h * 8 + e][nl]);
      *(short8*)(dst + h * 8) = o;
    }
  }
}

// ---------------------------------------------------------------------------
// Shared helpers.
// ---------------------------------------------------------------------------
#define GLOAD_LDS(g, l)                                                      \
  __builtin_amdgcn_global_load_lds(                                          \
      (const __attribute__((address_space(1))) void*)(g),                    \
      (__attribute__((address_space(3))) void*)(l), 16, 0, 0)

#define BARR do { asm volatile("" ::: "memory");                             \
                  __builtin_amdgcn_s_barrier();                              \
                  asm volatile("" ::: "memory"); } while (0)

#define VMW(n) asm volatile("s_waitcnt vmcnt(" #n ")" ::: "memory")

// counted lgkm wait + sched_barrier (rule #18: keep MFMA after the wait)
#define LGKMC(n) do { asm volatile("s_waitcnt lgkmcnt(" #n ")" ::: "memory"); \
                      __builtin_amdgcn_sched_barrier(0); } while (0)

// Stage 128 rows x 64 K bf16 (16 KB); 2 gload_lds per wave, 8 waves cover it.
__device__ __forceinline__ void stage_half(const short* __restrict__ src,
                                           size_t row0, int kOff, short* dst,
                                           int stride, int w, int rsub, int kc) {
  const short* g0 = src + (row0 + (size_t)(w * 8 + rsub)) * (size_t)stride
                    + kOff + kc * 8;
  GLOAD_LDS(g0, dst + w * 512);
  GLOAD_LDS(g0 + (size_t)64 * stride, dst + 4096 + w * 512);
}

// Fragment reads for the 8-wave (2Mx4N) map over 128x128 quadrants.
#define RD_A8(dst, base) do {                                                \
  _Pragma("unroll") for (int mt = 0; mt < 4; ++mt)                           \
  _Pragma("unroll") for (int kk = 0; kk < 2; ++kk)                           \
    dst[mt * 2 + kk] = *(const short8*)((base) +                             \
        (pm * 64 + mt * 16 + ln) * 64 + (((kk * 4 + quad) ^ l7) << 3));      \
} while (0)

#define RD_B4(dst, base) do {                                                \
  _Pragma("unroll") for (int nt = 0; nt < 2; ++nt)                           \
  _Pragma("unroll") for (int kk = 0; kk < 2; ++kk)                           \
    dst[nt * 2 + kk] = *(const short8*)((base) +                             \
        (pn * 32 + nt * 16 + ln) * 64 + (((kk * 4 + quad) ^ l7) << 3));      \
} while (0)

#define MFMA16(ACC, ar, br) do {                                             \
  __builtin_amdgcn_s_setprio(1);                                             \
  _Pragma("unroll") for (int mt = 0; mt < 4; ++mt)                           \
  _Pragma("unroll") for (int nt = 0; nt < 2; ++nt)                           \
  _Pragma("unroll") for (int kk = 0; kk < 2; ++kk)                           \
    ACC[mt][nt] = __builtin_amdgcn_mfma_f32_16x16x32_bf16(                   \
        ar[mt * 2 + kk], br[nt * 2 + kk], ACC[mt][nt], 0, 0, 0);             \
  __builtin_amdgcn_s_setprio(0);                                             \
} while (0)

// ---------------------------------------------------------------------------
// 256x256 GEMM, fragment-level software-pipelined 8-phase schedule.
// Reads issued in phase p feed the MFMA of phase p+1 (counted lgkmcnt(N),
// N = reads just issued, proves older reads landed while new stay in
// flight).  Quadrants per tile: Q1(a0,b0) Q2(a0,b1) Q3(a1,b1) Q4(a1,b0);
// per-phase reads 4/8/8/4.  Staging: tile t+2 into the buffer freed by
// tile t (region last-read >=2 barriers earlier; verified per-region).
// Graded VMW(8) BEFORE the phase-end barrier (cross-wave publish), one
// barrier per phase.  Steady-state invariant: 8 loads outstanding entering
// ph1 (= next tile's 4 half-tiles); each VMW completes exactly the
// half-tile(s) read next phase, uniform >=5-phase slack.  Last iteration
// degrades 6/4/0.  Register banks: a0,a1,b1 single (WAR-separated by >=1
// phase), b0 double (b0E/b0O per tile parity).
// ---------------------------------------------------------------------------
__device__ __forceinline__ void gemm256_pipe(
    const short* __restrict__ A, const short* __restrict__ BT,
    int K, int NT, size_t rowA0, size_t rowB0, short* lds,
    f32x4 acc[2][2][4][2], int w, int lane) {
  const int quad = lane >> 4, ln = lane & 15, l7 = lane & 7;
  const int pm = w >> 2, pn = w & 3;
  const int rsub = lane >> 3, kc = (lane & 7) ^ rsub;
  short* const Ab0 = lds;                // even-tile A (halves +0 / +8192)
  short* const Ab1 = lds + 16384;        // odd-tile  A
  short* const Bb0 = lds + 32768;        // even-tile B
  short* const Bb1 = lds + 49152;        // odd-tile  B

  short8 a0[8], a1[8], b1[4], b0E[4], b0O[4];

  if (NT == 1) {                         // single K-tile (tail2): 1 barrier
    stage_half(A,  rowA0,       0, Ab0,        K, w, rsub, kc);
    stage_half(BT, rowB0,       0, Bb0,        K, w, rsub, kc);
    stage_half(BT, rowB0 + 128, 0, Bb0 + 8192, K, w, rsub, kc);
    stage_half(A,  rowA0 + 128, 0, Ab0 + 8192, K, w, rsub, kc);
    VMW(0);
    BARR;
    RD_A8(a0, Ab0); RD_B4(b0E, Bb0);
    RD_B4(b1, Bb0 + 8192); RD_A8(a1, Ab0 + 8192);
    LGKMC(0);
    MFMA16(acc[0][0], a0, b0E);
    MFMA16(acc[0][1], a0, b1);
    MFMA16(acc[1][1], a1, b1);
    MFMA16(acc[1][0], a1, b0E);
    return;
  }

  // prologue: t0 full (8), t1 A0+B0 (4) -> VMW(4) completes all of t0;
  // read a0/b0E(t0); then t1 B1+A1 (4) -> invariant 8 outstanding.
  stage_half(A,  rowA0,       0,  Ab0,        K, w, rsub, kc);
  stage_half(BT, rowB0,       0,  Bb0,        K, w, rsub, kc);
  stage_half(BT, rowB0 + 128, 0,  Bb0 + 8192, K, w, rsub, kc);
  stage_half(A,  rowA0 + 128, 0,  Ab0 + 8192, K, w, rsub, kc);
  stage_half(A,  rowA0,       64, Ab1,        K, w, rsub, kc);
  stage_half(BT, rowB0,       64, Bb1,        K, w, rsub, kc);
  VMW(4);
  BARR;
  RD_A8(a0, Ab0);
  RD_B4(b0E, Bb0);
  stage_half(BT, rowB0 + 128, 64, Bb1 + 8192, K, w, rsub, kc);
  stage_half(A,  rowA0 + 128, 64, Ab1 + 8192, K, w, rsub, kc);

  const int NI = NT >> 1;
  for (int i = 0; i < NI; ++i) {
    const int t0 = 2 * i;
    const bool more = (t0 + 2 < NT);
    const int ku0 = (t0 + 2) << 6, ku1 = (t0 + 3) << 6;
    // ---- ph1: Q1(t0) = a0*b0E | read b1(t0) ----
    RD_B4(b1, Bb0 + 8192);
    LGKMC(4);
    MFMA16(acc[0][0], a0, b0E);
    BARR;
    // ---- ph2: Q2(t0) = a0*b1 | read a1(t0); stage A0(t0+2) ----
    RD_A8(a1, Ab0 + 8192);
    if (more) stage_half(A, rowA0, ku0, Ab0, K, w, rsub, kc);
    LGKMC(8);
    MFMA16(acc[0][1], a0, b1);
    if (more) { VMW(8); } else { VMW(6); }   // publishes t1-A0 for ph3
    BARR;
    // ---- ph3: Q3(t0) = a1*b1 | read a0(t1); stage B0(t0+2) ----
    RD_A8(a0, Ab1);
    if (more) stage_half(BT, rowB0, ku0, Bb0, K, w, rsub, kc);
    LGKMC(8);
    MFMA16(acc[1][1], a1, b1);
    if (more) { VMW(8); } else { VMW(4); }   // publishes t1-B0 for ph4
    BARR;
    // ---- ph4: Q4(t0) = a1*b0E | read b0O(t1); stage B1,A1(t0+2) ----
    RD_B4(b0O, Bb1);
    if (more) {
      stage_half(BT, rowB0 + 128, ku0, Bb0 + 8192, K, w, rsub, kc);
      stage_half(A,  rowA0 + 128, ku0, Ab0 + 8192, K, w, rsub, kc);
    }
    LGKMC(4);
    MFMA16(acc[1][0], a1, b0E);
    if (more) { VMW(8); } else { VMW(0); }   // publishes t1-B1,A1 for ph5/6
    BARR;
    // ---- ph5: Q1(t1) = a0*b0O | read b1(t1) ----
    RD_B4(b1, Bb1 + 8192);
    LGKMC(4);
    MFMA16(acc[0][0], a0, b0O);
    BARR;
    // ---- ph6: Q2(t1) = a0*b1 | read a1(t1); stage A0(t0+3) ----
    RD_A8(a1, Ab1 + 8192);
    if (more) stage_half(A, rowA0, ku1, Ab1, K, w, rsub, kc);
    LGKMC(8);
    MFMA16(acc[0][1], a0, b1);
    if (more) { VMW(8); }                    // publishes t2-A0 for ph7
    BARR;
    // ---- ph7: Q3(t1) = a1*b1 | read a0(t0+2); stage B0(t0+3) ----
    if (more) {
      RD_A8(a0, Ab0);
      stage_half(BT, rowB0, ku1, Bb1, K, w, rsub, kc);
      LGKMC(8);
    } else {
      LGKMC(0);
    }
    MFMA16(acc[1][1], a1, b1);
    if (more) { VMW(8); }                    // publishes t2-B0 for ph8
    BARR;
    // ---- ph8: Q4(t1) = a1*b0O | read b0E(t0+2); stage B1,A1(t0+3) ----
    if (more) {
      RD_B4(b0E, Bb0);
      stage_half(BT, rowB0 + 128, ku1, Bb1 + 8192, K, w, rsub, kc);
      stage_half(A,  rowA0 + 128, ku1, Ab1 + 8192, K, w, rsub, kc);
      LGKMC(4);
    } else {
      LGKMC(0);
    }
    MFMA16(acc[1][0], a1, b0O);
    if (more) { VMW(8); }                    // publishes t2-B1,A1 for next ph1/2
    BARR;
  }
}

// C/D layout: col = lane&15, row = (lane>>4)*4 + reg   [verified m89/m91]

// Exp-sum epilogue over the 256x256 accumulator -> ps[row][cs] partials.
__device__ __forceinline__ void exp_epilogue(
    f32x4 acc[2][2][4][2], const float* __restrict__ bias,
    float* __restrict__ ps, size_t c0, int Ncols, int nsplit, int r0,
    short* lds, int tid, int w, int lane) {
  const int quad = lane >> 4, ln = lane & 15;
  const int pm = w >> 2, pn = w & 3;
  float bv[2][2];
#pragma unroll
  for (int qb = 0; qb < 2; ++qb)
#pragma unroll
    for (int nt = 0; nt < 2; ++nt) {
      const size_t cg = c0 + qb * 128 + pn * 32 + nt * 16 + ln;
      bv[qb][nt] = (cg < (size_t)Ncols) ? bias[cg] : -1.0e30f;  // pad -> 0
    }
  float* const psF = (float*)lds;  // [pn][qb][256] = 8 KB (LDS reuse)
  BARR;                            // all K-loop LDS activity complete
#pragma unroll
  for (int qa = 0; qa < 2; ++qa)
#pragma unroll
    for (int qb = 0; qb < 2; ++qb)
#pragma unroll
      for (int mt = 0; mt < 4; ++mt)
#pragma unroll
        for (int r = 0; r < 4; ++r) {
          float s = __expf(acc[qa][qb][mt][0][r] + bv[qb][0]) +
                    __expf(acc[qa][qb][mt][1][r] + bv[qb][1]);
#pragma unroll
          for (int off = 1; off < 16; off <<= 1) s += __shfl_xor(s, off, 64);
          if (ln == 0)
            psF[(pn * 2 + qb) * 256 + qa * 128 + pm * 64 + mt * 16 + quad * 4 + r] = s;
        }
  BARR;
  {
    const int qb = tid >> 8, row = tid & 255;
    const int cs = (int)(c0 >> 7) + qb;
    if (cs < nsplit)
      ps[(size_t)(r0 + row) * nsplit + cs] =
          psF[(0 * 2 + qb) * 256 + row] + psF[(1 * 2 + qb) * 256 + row] +
          psF[(2 * 2 + qb) * 256 + row] + psF[(3 * 2 + qb) * 256 + row];
  }
}

// ---------------------------------------------------------------------------
// 128x128-tile MFMA main loop (4-wave) — used by proj_all only.
// ---------------------------------------------------------------------------
__device__ __forceinline__ void mfma_mainloop(const short* aB[4], const short* bB[4],
                                              short* As, short* Bs,
                                              f32x4 acc[4][4],
                                              int K, int w, int lane) {
  const int quad = lane >> 4, ln = lane & 15;
  const int wm = w >> 1, wn = w & 1;
  const int l7 = ln & 7;
  for (int kt = 0; kt < K; kt += 64) {
#pragma unroll
    for (int i = 0; i < 4; ++i) {
      const int row = w * 32 + i * 8;
      __builtin_amdgcn_global_load_lds(
          (const __attribute__((address_space(1))) void*)(aB[i] + kt),
          (__attribute__((address_space(3))) void*)(As + row * 64), 16, 0, 0);
      __builtin_amdgcn_global_load_lds(
          (const __attribute__((address_space(1))) void*)(bB[i] + kt),
          (__attribute__((address_space(3))) void*)(Bs + row * 64), 16, 0, 0);
    }
    __syncthreads();
#pragma unroll
    for (int ks = 0; ks < 2; ++ks) {
      const int kcs = ks * 4 + quad;
      short8 af[4], bfr[4];
#pragma unroll
      for (int mt = 0; mt < 4; ++mt) {
        const int row = wm * 64 + mt * 16 + ln;
        af[mt] = *(const short8*)(As + ((row * 8 + (kcs ^ l7)) << 3));
      }
#pragma unroll
      for (int nt = 0; nt < 4; ++nt) {
        const int rowb = wn * 64 + nt * 16 + ln;
        bfr[nt] = *(const short8*)(Bs + ((rowb * 8 + (kcs ^ l7)) << 3));
      }
#pragma unroll
      for (int mt = 0; mt < 4; ++mt)
#pragma unroll
        for (int nt = 0; nt < 4; ++nt)
          acc[mt][nt] = __builtin_amdgcn_mfma_f32_16x16x32_bf16(
              af[mt], bfr[nt], acc[mt][nt], 0, 0, 0);
    }
    __syncthreads();
  }
}

// ---------------------------------------------------------------------------
// PROJ_ALL (176 blocks, 256 thr): head proj + tail projs on compacted rows.
// ---------------------------------------------------------------------------
__global__ __launch_bounds__(256) void proj_all(
    const short* __restrict__ xb,
    const short* __restrict__ WpT0, const short* __restrict__ WpT1,
    const short* __restrict__ WpT2,
    short* __restrict__ P0b, short* __restrict__ P1c, short* __restrict__ P2c,
    const int* __restrict__ rows1, const int* __restrict__ rows2,
    const int* __restrict__ counts) {
  int b = blockIdx.x;
  const short* BT; short* C; int N, r0, c0, cnt;
  const int* rowlist = nullptr;
  if (b < 128) {
    BT = WpT0; C = P0b; N = 1024;
    c0 = (b & 7) * 128; r0 = (b >> 3) * 128; cnt = NROWS;
  } else if (b < 160) {
    b -= 128; BT = WpT1; C = P1c; N = 256;
    c0 = (b & 1) * 128; r0 = (b >> 1) * 128; rowlist = rows1; cnt = counts[1];
  } else {
    b -= 160; BT = WpT2; C = P2c; N = 64;
    c0 = 0; r0 = b * 128; rowlist = rows2; cnt = counts[2];
  }
  if (r0 >= cnt) return;

  __shared__ short As[128 * 64];
  __shared__ short Bs[128 * 64];
  const int tid = threadIdx.x;
  const int w = tid >> 6, lane = tid & 63;
  const int quad = lane >> 4, ln = lane & 15;
  const int wm = w >> 1, wn = w & 1;
  const int rsub = lane >> 3;
  const int kc = (lane & 7) ^ rsub;
  const int K = 1024;

  const short* aB[4]; const short* bB[4];
#pragma unroll
  for (int i = 0; i < 4; ++i) {
    const int sl = r0 + w * 32 + i * 8 + rsub;
    const int ar = rowlist ? rowlist[sl < cnt ? sl : cnt - 1] : sl;
    aB[i] = xb + (size_t)ar * K + kc * 8;
    bB[i] = BT + (size_t)(c0 + w * 32 + i * 8 + rsub) * K + kc * 8;
  }

  f32x4 acc[4][4];
  const f32x4 zero = {0.f, 0.f, 0.f, 0.f};
#pragma unroll
  for (int i = 0; i < 4; ++i)
#pragma unroll
    for (int j = 0; j < 4; ++j) acc[i][j] = zero;
  mfma_mainloop(aB, bB, As, Bs, acc, K, w, lane);
#pragma unroll
  for (int mt = 0; mt < 4; ++mt)
#pragma unroll
    for (int r = 0; r < 4; ++r) {
      const int grow = r0 + wm * 64 + mt * 16 + quad * 4 + r;
#pragma unroll
      for (int nt = 0; nt < 4; ++nt) {
        const int cg = c0 + wn * 64 + nt * 16 + ln;
        if (cg < N) C[(size_t)grow * N + cg] = f2bf(acc[mt][nt][r]);
      }
    }
}

// ---------------------------------------------------------------------------
// LOGIT_FUSED (2896 blocks x 512 thr, homogeneous 256x256 pipelined blocks):
//   blocks 0..319     head  (8 rb x 40 cb, XCD-partitioned cols, K=1024)
//   blocks 320..1263  tail1 (8 rb x 118 cb, K=256, NT=4)
//   blocks 1264..2895 tail2 (8 rb x 204 cb, K=64,  NT=1)
// Heads dispatched first so tails pack the remaining CUs.
// ---------------------------------------------------------------------------
__global__ __launch_bounds__(512, 2) void logit_fused(
    const short* __restrict__ P0b, const short* __restrict__ WlT0,
    const float* __restrict__ bl0, float* __restrict__ psh,
    const short* __restrict__ P1c, const short* __restrict__ WlT1,
    const float* __restrict__ bl1, float* __restrict__ ps1,
    const short* __restrict__ P2c, const short* __restrict__ WlT2,
    const float* __restrict__ bl2, float* __restrict__ ps2,
    const int* __restrict__ counts) {
  __shared__ short lds[65536];   // 128 KiB (aliased for psF in the epilogue)
  const int tid = threadIdx.x;
  const int w = tid >> 6, lane = tid & 63;
  const int b = blockIdx.x;

  const short* A; const short* BT; const float* bias; float* ps;
  int K, NT, Ncols, nsplit, r0; size_t c0;
  if (b < 320) {                       // ---- head ----
    const int xcd = b & 7, j = b >> 3;
    const int cb = xcd * 5 + j % 5, rb = j / 5;
    r0 = rb * 256; c0 = (size_t)cb * 256;
    A = P0b; BT = WlT0; bias = bl0; ps = psh;
    K = 1024; NT = 16; Ncols = 10000; nsplit = 79;
  } else if (b < 1264) {               // ---- tail1 ----
    const int b1 = b - 320;
    const int rb = b1 / 118, cb = b1 % 118;
    r0 = rb * 256;
    if (r0 >= counts[1]) return;
    c0 = (size_t)cb * 256;
    A = P1c; BT = WlT1; bias = bl1; ps = ps1;
    K = 256; NT = 4; Ncols = 30000; nsplit = 235;
  } else {                             // ---- tail2 ----
    const int b2 = b - 1264;
    const int rb = b2 / 204, cb = b2 % 204;
    r0 = rb * 256;
    if (r0 >= counts[2]) return;
    c0 = (size_t)cb * 256;
    A = P2c; BT = WlT2; bias = bl2; ps = ps2;
    K = 64; NT = 1; Ncols = 52000; nsplit = 407;
  }

  f32x4 acc[2][2][4][2];
  const f32x4 zero = {0.f, 0.f, 0.f, 0.f};
#pragma unroll
  for (int qa = 0; qa < 2; ++qa)
#pragma unroll
    for (int qb = 0; qb < 2; ++qb)
#pragma unroll
      for (int mt = 0; mt < 4; ++mt)
#pragma unroll
        for (int nt = 0; nt < 2; ++nt) acc[qa][qb][mt][nt] = zero;

  gemm256_pipe(A, BT, K, NT, (size_t)r0, c0, lds, acc, w, lane);
  exp_epilogue(acc, bias, ps, c0, Ncols, nsplit, r0, lds, tid, w, lane);
}

// ---------------------------------------------------------------------------
// FINALIZE: one wave per row (unchanged).
// ---------------------------------------------------------------------------
__global__ __launch_bounds__(256) void finalize(
    const short* __restrict__ P0b, const short* __restrict__ P1c,
    const short* __restrict__ P2c,
    const short* __restrict__ WlT0, const float* __restrict__ bl0,
    const short* __restrict__ WlT1, const float* __restrict__ bl1,
    const short* __restrict__ WlT2, const float* __restrict__ bl2,
    const float* __restrict__ Wc, const float* __restrict__ bc,
    const int* __restrict__ y, const int* __restrict__ slot_of_row,
    const float* __restrict__ psh, const float* __restrict__ ps1,
    const float* __restrict__ ps2, float* __restrict__ out) {
  const int lane = threadIdx.x & 63;
  const int row = blockIdx.x * 4 + (threadIdx.x >> 6);

  float a0 = 0.f, a1 = 0.f;
  for (int k = lane; k < HID; k += 64) {
    const float p = bf2f(P0b[(size_t)row * HID + k]);
    a0 += p * Wc[2 * k];
    a1 += p * Wc[2 * k + 1];
  }
  a0 = wave_sum(a0);
  a1 = wave_sum(a1);
  const float cl0 = a0 + bc[0], cl1 = a1 + bc[1];

  float S = 0.f;
  for (int i = lane; i < 79; i += 64) S += psh[(size_t)row * 79 + i];
  S = wave_sum(S) + __expf(cl0) + __expf(cl1);
  const float lse = logf(S);

  const int yy = y[row];
  float nll;
  if (yy < 10000) {
    const short* pr = P0b + (size_t)row * 1024;
    const short* wr = WlT0 + (size_t)yy * 1024;
    float a = 0.f;
    for (int kk = lane * 4; kk < 1024; kk += 256) {
      const short4_t p = *(const short4_t*)(pr + kk);
      const short4_t wv = *(const short4_t*)(wr + kk);
      a += bf2f(p.x) * bf2f(wv.x) + bf2f(p.y) * bf2f(wv.y)
         + bf2f(p.z) * bf2f(wv.z) + bf2f(p.w) * bf2f(wv.w);
    }
    a = wave_sum(a);
    nll = -((a + bl0[yy]) - lse);
  } else if (yy < 20000) {
    const int t = yy - 10000;
    const int slot = slot_of_row[row];
    float S1 = 0.f;
    for (int i = lane; i < 235; i += 64) S1 += ps1[(size_t)slot * 235 + i];
    S1 = wave_sum(S1);
    const short* pr = P1c + (size_t)slot * 256;
    const short* wr = WlT1 + (size_t)t * 256;
    const int kk = lane * 4;
    const short4_t p = *(const short4_t*)(pr + kk);
    const short4_t wv = *(const short4_t*)(wr + kk);
    float a = bf2f(p.x) * bf2f(wv.x) + bf2f(p.y) * bf2f(wv.y)
            + bf2f(p.z) * bf2f(wv.z) + bf2f(p.w) * bf2f(wv.w);
    a = wave_sum(a);
    nll = -((cl1 - lse) + ((a + bl1[t]) - logf(S1)));
  } else {
    const int t = yy - 20000;
    const int slot = slot_of_row[row];
    float S2 = 0.f;
    for (int i = lane; i < 407; i += 64) S2 += ps2[(size_t)slot * 407 + i];
    S2 = wave_sum(S2);
    float a = 0.f;
    if (lane < 16) {
      const short* pr = P2c + (size_t)slot * 64;
      const short* wr = WlT2 + (size_t)t * 64;
      const int kk = lane * 4;
      const short4_t p = *(const short4_t*)(pr + kk);
      const short4_t wv = *(const short4_t*)(wr + kk);
      a = bf2f(p.x) * bf2f(wv.x) + bf2f(p.y) * bf2f(wv.y)
        + bf2f(p.z) * bf2f(wv.z) + bf2f(p.w) * bf2f(wv.w);
    }
    a = wave_sum(a);
    nll = -((cl0 - lse) + ((a + bl2[t]) - logf(S2)));
  }
  if (lane == 0) out[row] = nll;
}

// ---------------------------------------------------------------------------
extern "C" void kernel_launch(void* const* d_in, const int* in_sizes, int n_in,
                              void* d_out, int out_size, void* d_ws, size_t ws_size,
                              hipStream_t stream) {
  const float* x   = (const float*)d_in[0];
  const int*   y   = (const int*)d_in[1];
  const float* Wp0 = (const float*)d_in[2];
  const float* Wp1 = (const float*)d_in[3];
  const float* Wp2 = (const float*)d_in[4];
  const float* Wl0 = (const float*)d_in[5];
  const float* bl0 = (const float*)d_in[6];
  const float* Wl1 = (const float*)d_in[7];
  const float* bl1 = (const float*)d_in[8];
  const float* Wl2 = (const float*)d_in[9];
  const float* bl2 = (const float*)d_in[10];
  const float* Wc  = (const float*)d_in[11];
  const float* bc  = (const float*)d_in[12];
  float* out = (float*)d_out;

  float* fws = (float*)d_ws;
  float* psh = fws; fws += (size_t)NROWS * 79;
  float* ps1 = fws; fws += (size_t)NROWS * 235;
  float* ps2 = fws; fws += (size_t)NROWS * 407;
  int* iws = (int*)fws;
  int* counts      = iws; iws += 4;
  int* slot_of_row = iws; iws += NROWS;
  int* rows1       = iws; iws += NROWS;
  int* rows2       = iws; iws += NROWS;
  short* sp = (short*)iws;
  short* xb   = sp; sp += (size_t)NROWS * 1024;
  short* P0b  = sp; sp += (size_t)NROWS * 1024;
  short* P1c  = sp; sp += (size_t)NROWS * 256;
  short* P2c  = sp; sp += (size_t)NROWS * 64;
  short* WpT0 = sp; sp += (size_t)1024 * 1024;
  short* WpT1 = sp; sp += (size_t)256 * 1024;
  short* WpT2 = sp; sp += (size_t)128 * 1024;
  short* WlT0 = sp; sp += (size_t)10240 * 1024;
  short* WlT1 = sp; sp += (size_t)30208 * 256;
  short* WlT2 = sp; sp += (size_t)52224 * 64;

  dim3 blk(256);
  prep<<<dim3(6129), blk, 0, stream>>>(x, y, Wp0, Wp1, Wp2, Wl0, Wl1, Wl2,
                                       xb, counts, slot_of_row, rows1, rows2,
                                       WpT0, WpT1, WpT2, WlT0, WlT1, WlT2);
  proj_all<<<dim3(176), blk, 0, stream>>>(xb, WpT0, WpT1, WpT2, P0b, P1c, P2c,
                                          rows1, rows2, counts);
  logit_fused<<<dim3(2896), dim3(512), 0, stream>>>(
      P0b, WlT0, bl0, psh, P1c, WlT1, bl1, ps1, P2c, WlT2, bl2, ps2, counts);
  finalize<<<dim3(NROWS / 4), blk, 0, stream>>>(
      P0b, P1c, P2c, WlT0, bl0, WlT1, bl1, WlT2, bl2, Wc, bc, y, slot_of_row,
      psh, ps1, ps2, out);
}

// Round 7
// 305.652 us; speedup vs baseline: 1.3155x; 1.3155x over previous
//
#include <hip/hip_runtime.h>
#include <math.h>

#define HID 1024
#define NROWS 2048

typedef __attribute__((ext_vector_type(8))) short short8;
typedef __attribute__((ext_vector_type(4))) short short4_t;
typedef __attribute__((ext_vector_type(4))) float f32x4;

__device__ __forceinline__ short f2bf(float f) {
  union { float f; unsigned u; } v; v.f = f;
  unsigned r = v.u + 0x7fffu + ((v.u >> 16) & 1u);
  return (short)(r >> 16);
}
__device__ __forceinline__ float bf2f(short s) {
  union { unsigned u; float f; } v; v.u = ((unsigned)(unsigned short)s) << 16;
  return v.f;
}
__device__ __forceinline__ float wave_sum(float a) {
#pragma unroll
  for (int off = 32; off; off >>= 1) a += __shfl_xor(a, off, 64);
  return a;
}

// ---------------------------------------------------------------------------
// PREP: block 0 = classify; blocks 1..512 = x fp32->bf16 (16 elem/thread);
// blocks 513.. = 64x64 transposes (fp32 [K,N] -> bf16 [Npad,K]).
// Transpose blocks: 256+64+32+2560+1888+816 = 5616.  Grid = 6129.
// ---------------------------------------------------------------------------
__global__ __launch_bounds__(256) void prep(
    const float* __restrict__ x, const int* __restrict__ y,
    const float* __restrict__ Wp0, const float* __restrict__ Wp1,
    const float* __restrict__ Wp2, const float* __restrict__ Wl0,
    const float* __restrict__ Wl1, const float* __restrict__ Wl2,
    short* __restrict__ xb,
    int* __restrict__ counts, int* __restrict__ slot_of_row,
    int* __restrict__ rows1, int* __restrict__ rows2,
    short* __restrict__ T0, short* __restrict__ T1, short* __restrict__ T2,
    short* __restrict__ T3, short* __restrict__ T4, short* __restrict__ T5) {
  const int tid = threadIdx.x;
  int b = blockIdx.x;
  if (b == 0) {                       // ---- classify ----
    __shared__ int c1s, c2s;
    if (tid == 0) { c1s = 0; c2s = 0; }
    __syncthreads();
    for (int r = tid; r < NROWS; r += 256) {
      const int yy = y[r];
      if (yy >= 20000) {
        const int s = atomicAdd(&c2s, 1);
        slot_of_row[r] = s; rows2[s] = r;
      } else if (yy >= 10000) {
        const int s = atomicAdd(&c1s, 1);
        slot_of_row[r] = s; rows1[s] = r;
      } else {
        slot_of_row[r] = -1;
      }
    }
    __syncthreads();
    if (tid == 0) { counts[0] = NROWS; counts[1] = c1s; counts[2] = c2s; }
    return;
  }
  if (b <= 512) {                     // ---- cvt x: 4 float4 rounds ----
    const int base = (b - 1) * 4096;
#pragma unroll
    for (int j = 0; j < 4; ++j) {
      const int i = base + j * 1024 + tid * 4;
      const float4 v = *(const float4*)&x[i];
      short4_t o;
      o.x = f2bf(v.x); o.y = f2bf(v.y); o.z = f2bf(v.z); o.w = f2bf(v.w);
      *(short4_t*)&xb[i] = o;
    }
    return;
  }
  b -= 513;                           // ---- 64x64 transposes ----
  const float* W; short* BT; int K, N, Npad, tn;
  if (b < 256)               { W = Wp0; BT = T0; K = 1024; N = 1024;  Npad = 1024;  tn = 16;  }
  else if ((b -= 256) < 64)  { W = Wp1; BT = T1; K = 1024; N = 256;   Npad = 256;   tn = 4;   }
  else if ((b -= 64) < 32)   { W = Wp2; BT = T2; K = 1024; N = 64;    Npad = 128;   tn = 2;   }
  else if ((b -= 32) < 2560) { W = Wl0; BT = T3; K = 1024; N = 10000; Npad = 10240; tn = 160; }
  else if ((b -= 2560) < 1888){W = Wl1; BT = T4; K = 256;  N = 30000; Npad = 30208; tn = 472; }
  else { b -= 1888;            W = Wl2; BT = T5; K = 64;   N = 52000; Npad = 52224; tn = 816; }

  __shared__ float T[64][65];
  const int n0 = (b % tn) * 64, k0 = (b / tn) * 64;
  const int rr = tid >> 4, cc = (tid & 15) * 4;
#pragma unroll
  for (int j = 0; j < 4; ++j) {
    const int kr = rr + j * 16;
    const float* p = &W[(size_t)(k0 + kr) * N + n0 + cc];
    float v0 = 0.f, v1 = 0.f, v2 = 0.f, v3 = 0.f;
    if (n0 + cc + 3 < N) {
      const float4 v = *(const float4*)p;
      v0 = v.x; v1 = v.y; v2 = v.z; v3 = v.w;
    } else {
      if (n0 + cc + 0 < N) v0 = p[0];
      if (n0 + cc + 1 < N) v1 = p[1];
      if (n0 + cc + 2 < N) v2 = p[2];
    }
    T[kr][cc] = v0; T[kr][cc + 1] = v1; T[kr][cc + 2] = v2; T[kr][cc + 3] = v3;
  }
  __syncthreads();
  const int nl = tid >> 2, ks = (tid & 3) * 16;
  const int n = n0 + nl;
  if (n < Npad) {
    const bool z = (n >= N);
    short* dst = &BT[(size_t)n * K + k0 + ks];
#pragma unroll
    for (int h = 0; h < 2; ++h) {
      short8 o;
#pragma unroll
      for (int e = 0; e < 8; ++e)
        o[e] = z ? (short)0 : f2bf(T[ks + h * 8 + e][nl]);
      *(short8*)(dst + h * 8) = o;
    }
  }
}

// ---------------------------------------------------------------------------
// Shared helpers.
// ---------------------------------------------------------------------------
#define GLOAD_LDS(g, l)                                                      \
  __builtin_amdgcn_global_load_lds(                                          \
      (const __attribute__((address_space(1))) void*)(g),                    \
      (__attribute__((address_space(3))) void*)(l), 16, 0, 0)

#define BARR do { asm volatile("" ::: "memory");                             \
                  __builtin_amdgcn_s_barrier();                              \
                  asm volatile("" ::: "memory"); } while (0)

#define VMW(n) asm volatile("s_waitcnt vmcnt(" #n ")" ::: "memory")

// Stage 128 rows x 64 K bf16 (16 KB); 2 gload_lds per wave, 8 waves cover it.
__device__ __forceinline__ void stage_half(const short* __restrict__ src,
                                           size_t row0, int kOff, short* dst,
                                           int stride, int w, int rsub, int kc) {
  const short* g0 = src + (row0 + (size_t)(w * 8 + rsub)) * (size_t)stride
                    + kOff + kc * 8;
  GLOAD_LDS(g0, dst + w * 512);
  GLOAD_LDS(g0 + (size_t)64 * stride, dst + 4096 + w * 512);
}

// ---------------------------------------------------------------------------
// 128x128-tile MFMA main loop (4-wave) — proj_all and logit_tails.
// ---------------------------------------------------------------------------
__device__ __forceinline__ void mfma_mainloop(const short* aB[4], const short* bB[4],
                                              short* As, short* Bs,
                                              f32x4 acc[4][4],
                                              int K, int w, int lane) {
  const int quad = lane >> 4, ln = lane & 15;
  const int wm = w >> 1, wn = w & 1;
  const int l7 = ln & 7;
  for (int kt = 0; kt < K; kt += 64) {
#pragma unroll
    for (int i = 0; i < 4; ++i) {
      const int row = w * 32 + i * 8;
      __builtin_amdgcn_global_load_lds(
          (const __attribute__((address_space(1))) void*)(aB[i] + kt),
          (__attribute__((address_space(3))) void*)(As + row * 64), 16, 0, 0);
      __builtin_amdgcn_global_load_lds(
          (const __attribute__((address_space(1))) void*)(bB[i] + kt),
          (__attribute__((address_space(3))) void*)(Bs + row * 64), 16, 0, 0);
    }
    __syncthreads();
#pragma unroll
    for (int ks = 0; ks < 2; ++ks) {
      const int kcs = ks * 4 + quad;
      short8 af[4], bfr[4];
#pragma unroll
      for (int mt = 0; mt < 4; ++mt) {
        const int row = wm * 64 + mt * 16 + ln;
        af[mt] = *(const short8*)(As + ((row * 8 + (kcs ^ l7)) << 3));
      }
#pragma unroll
      for (int nt = 0; nt < 4; ++nt) {
        const int rowb = wn * 64 + nt * 16 + ln;
        bfr[nt] = *(const short8*)(Bs + ((rowb * 8 + (kcs ^ l7)) << 3));
      }
#pragma unroll
      for (int mt = 0; mt < 4; ++mt)
#pragma unroll
        for (int nt = 0; nt < 4; ++nt)
          acc[mt][nt] = __builtin_amdgcn_mfma_f32_16x16x32_bf16(
              af[mt], bfr[nt], acc[mt][nt], 0, 0, 0);
    }
    __syncthreads();
  }
}

// C/D layout: col = lane&15, row = (lane>>4)*4 + reg   [verified m89/m91]

// ---------------------------------------------------------------------------
// PROJ_ALL (176 blocks, 256 thr): head proj + tail projs on compacted rows.
// ---------------------------------------------------------------------------
__global__ __launch_bounds__(256) void proj_all(
    const short* __restrict__ xb,
    const short* __restrict__ WpT0, const short* __restrict__ WpT1,
    const short* __restrict__ WpT2,
    short* __restrict__ P0b, short* __restrict__ P1c, short* __restrict__ P2c,
    const int* __restrict__ rows1, const int* __restrict__ rows2,
    const int* __restrict__ counts) {
  int b = blockIdx.x;
  const short* BT; short* C; int N, r0, c0, cnt;
  const int* rowlist = nullptr;
  if (b < 128) {
    BT = WpT0; C = P0b; N = 1024;
    c0 = (b & 7) * 128; r0 = (b >> 3) * 128; cnt = NROWS;
  } else if (b < 160) {
    b -= 128; BT = WpT1; C = P1c; N = 256;
    c0 = (b & 1) * 128; r0 = (b >> 1) * 128; rowlist = rows1; cnt = counts[1];
  } else {
    b -= 160; BT = WpT2; C = P2c; N = 64;
    c0 = 0; r0 = b * 128; rowlist = rows2; cnt = counts[2];
  }
  if (r0 >= cnt) return;

  __shared__ short As[128 * 64];
  __shared__ short Bs[128 * 64];
  const int tid = threadIdx.x;
  const int w = tid >> 6, lane = tid & 63;
  const int quad = lane >> 4, ln = lane & 15;
  const int wm = w >> 1, wn = w & 1;
  const int rsub = lane >> 3;
  const int kc = (lane & 7) ^ rsub;
  const int K = 1024;

  const short* aB[4]; const short* bB[4];
#pragma unroll
  for (int i = 0; i < 4; ++i) {
    const int sl = r0 + w * 32 + i * 8 + rsub;
    const int ar = rowlist ? rowlist[sl < cnt ? sl : cnt - 1] : sl;
    aB[i] = xb + (size_t)ar * K + kc * 8;
    bB[i] = BT + (size_t)(c0 + w * 32 + i * 8 + rsub) * K + kc * 8;
  }

  f32x4 acc[4][4];
  const f32x4 zero = {0.f, 0.f, 0.f, 0.f};
#pragma unroll
  for (int i = 0; i < 4; ++i)
#pragma unroll
    for (int j = 0; j < 4; ++j) acc[i][j] = zero;
  mfma_mainloop(aB, bB, As, Bs, acc, K, w, lane);
#pragma unroll
  for (int mt = 0; mt < 4; ++mt)
#pragma unroll
    for (int r = 0; r < 4; ++r) {
      const int grow = r0 + wm * 64 + mt * 16 + quad * 4 + r;
#pragma unroll
      for (int nt = 0; nt < 4; ++nt) {
        const int cg = c0 + wn * 64 + nt * 16 + ln;
        if (cg < N) C[(size_t)grow * N + cg] = f2bf(acc[mt][nt][r]);
      }
    }
}

// ---------------------------------------------------------------------------
// LOGIT_HEAD: 256x256 tile, BK=64, 8 waves (2Mx4N), 128 KiB LDS, graded
// 4-phase schedule (R1, measured 72.5 us, VGPR 120, no spill).
//   q1: issue A.h0(u+1)->buf[c^1]   reads: A-q0 (8) + B-nh0 (4)   MFMA(0,0)
//   q2: issue A.h1(u+1)->buf[c^1]   reads: B-nh1 (4)              MFMA(0,1)
//   q3: issue B.h0(u+2)->buf[c]     reads: A-q1 (8)               MFMA(1,1)
//   q4: issue B.h1(u+2)->buf[c]     + vmcnt(4) before final bar   MFMA(1,0)
// ---------------------------------------------------------------------------
#define RD_A(QM) do {                                                        \
  _Pragma("unroll") for (int mt = 0; mt < 4; ++mt) {                         \
    const int rL = ((QM) * 4 + mt) * 16 + ln;                                \
    _Pragma("unroll") for (int kk = 0; kk < 2; ++kk) {                       \
      const int kcs = kk * 4 + quad;                                         \
      aq[mt * 2 + kk] = *(const short8*)(Ah + rL * 64 + ((kcs ^ l7) << 3));  \
    } } } while (0)

#define RD_B(NH) do {                                                        \
  _Pragma("unroll") for (int nt = 0; nt < 2; ++nt) {                         \
    const int ntp = (NH) * 2 + nt;                                           \
    const int cL = cB + ntp * 16 + ln;                                       \
    _Pragma("unroll") for (int kk = 0; kk < 2; ++kk) {                       \
      const int kcs = kk * 4 + quad;                                         \
      bq[ntp * 2 + kk] = *(const short8*)(Bh + cL * 64 + ((kcs ^ l7) << 3)); \
    } } } while (0)

#define MFMA_Q(QM, QN) do {                                                  \
  __builtin_amdgcn_s_setprio(1);                                             \
  _Pragma("unroll") for (int mt = 0; mt < 4; ++mt)                           \
  _Pragma("unroll") for (int nt = 0; nt < 2; ++nt)                           \
  _Pragma("unroll") for (int kk = 0; kk < 2; ++kk)                           \
    acc[(QM) * 4 + mt][(QN) * 2 + nt] =                                      \
        __builtin_amdgcn_mfma_f32_16x16x32_bf16(                             \
            aq[mt * 2 + kk], bq[((QN) * 2 + nt) * 2 + kk],                   \
            acc[(QM) * 4 + mt][(QN) * 2 + nt], 0, 0, 0);                     \
  __builtin_amdgcn_s_setprio(0);                                             \
} while (0)

__global__ __launch_bounds__(512, 2) void logit_head(
    const short* __restrict__ P0b, const short* __restrict__ WlT0,
    const float* __restrict__ bl0, float* __restrict__ psh) {
  const int b = blockIdx.x;              // 320 blocks: 8 rb x 40 cb
  const int xcd = b & 7, j = b >> 3;
  const int cb = xcd * 5 + j % 5, rb = j / 5;   // 5 col-tiles per XCD (L2)
  const int r0 = rb * 256;
  const size_t c0 = (size_t)cb * 256;

  __shared__ short lds[65536];           // 128 KiB
  short* const Abase = lds;
  short* const Bbase = lds + 32768;

  const int tid = threadIdx.x;
  const int w = tid >> 6, lane = tid & 63;
  const int quad = lane >> 4, ln = lane & 15, l7 = lane & 7;
  const int wm = w >> 2, wn = w & 3;
  const int rsub = lane >> 3, kc = (lane & 7) ^ rsub;
  const int cB = (wn & 1) * 64;

  // prologue: tile0 (4 halves) + tile1 B halves -> VMW(4) waits tile0
  stage_half(P0b, (size_t)r0,        0,  Abase,          1024, w, rsub, kc);
  stage_half(P0b, (size_t)r0 + 128,  0,  Abase + 8192,   1024, w, rsub, kc);
  stage_half(WlT0, c0,               0,  Bbase,          1024, w, rsub, kc);
  stage_half(WlT0, c0 + 128,         0,  Bbase + 8192,   1024, w, rsub, kc);
  stage_half(WlT0, c0,               64, Bbase + 16384,  1024, w, rsub, kc);
  stage_half(WlT0, c0 + 128,         64, Bbase + 24576,  1024, w, rsub, kc);
  VMW(4);
  __builtin_amdgcn_s_barrier();
  asm volatile("" ::: "memory");

  f32x4 acc[8][4];
  const f32x4 zero = {0.f, 0.f, 0.f, 0.f};
#pragma unroll
  for (int i = 0; i < 8; ++i)
#pragma unroll
    for (int jj = 0; jj < 4; ++jj) acc[i][jj] = zero;

  short8 aq[8], bq[8];
  const short* const Ard = Abase + wm * 8192;
  const short* const Brd = Bbase + (wn >> 1) * 8192;

#pragma unroll 2
  for (int u = 0; u < 16; ++u) {
    const int c = u & 1;
    const short* Ah = Ard + c * 16384;
    const short* Bh = Brd + c * 16384;
    short* An = Abase + (c ^ 1) * 16384;
    short* Bn = Bbase + c * 16384;
    const int k1 = (u + 1) << 6, k2 = (u + 2) << 6;

    // ---- q1: quad(0,0) ----
    RD_A(0);
    RD_B(0);
    if (u < 15) stage_half(P0b, (size_t)r0, k1, An, 1024, w, rsub, kc);
    BARR;
    MFMA_Q(0, 0);
    BARR;
    // ---- q2: quad(0,1) ----
    RD_B(1);
    if (u < 15) stage_half(P0b, (size_t)r0 + 128, k1, An + 8192, 1024, w, rsub, kc);
    BARR;
    MFMA_Q(0, 1);
    BARR;
    // ---- q3: quad(1,1) ----
    RD_A(1);
    if (u < 14) stage_half(WlT0, c0, k2, Bn, 1024, w, rsub, kc);
    BARR;
    MFMA_Q(1, 1);
    BARR;
    // ---- q4: quad(1,0) ----
    if (u < 14) stage_half(WlT0, c0 + 128, k2, Bn + 8192, 1024, w, rsub, kc);
    BARR;
    MFMA_Q(1, 0);
    if (u < 14) { VMW(4); }
    else        { VMW(0); }
    BARR;
  }

  // epilogue: exp-sum partials per 128-col split (nsplit = 79)
  float bv[4];
#pragma unroll
  for (int nt = 0; nt < 4; ++nt) {
    const size_t cg = c0 + (size_t)wn * 64 + nt * 16 + ln;
    bv[nt] = (cg < 10000) ? bl0[cg] : -1.0e30f;  // pad cols -> exp = 0
  }
  float* psL = (float*)lds;  // [pn][qb][256] = 8 KB, LDS reuse
#pragma unroll
  for (int mt = 0; mt < 8; ++mt)
#pragma unroll
    for (int r = 0; r < 4; ++r) {
      float s = 0.f;
#pragma unroll
      for (int nt = 0; nt < 4; ++nt) s += __expf(acc[mt][nt][r] + bv[nt]);
#pragma unroll
      for (int off = 1; off < 16; off <<= 1) s += __shfl_xor(s, off, 64);
      if (ln == 0)
        psL[(wn & 1) * 512 + (wn >> 1) * 256 + wm * 128 + mt * 16 + quad * 4 + r] = s;
    }
  BARR;
  {
    const int sL = tid >> 8, rowL = tid & 255;
    const int csg = (int)(c0 >> 7) + sL;
    if (csg < 79)
      psh[(size_t)(r0 + rowL) * 79 + csg] =
          psL[sL * 256 + rowL] + psL[512 + sL * 256 + rowL];
  }
}

// ---------------------------------------------------------------------------
// LOGIT_TAILS: tail1 + tail2 on compacted rows, 128x128 structure,
// 33 KB LDS (~4 blocks/CU), XCD-partitioned col splits.  (R1, measured)
// ---------------------------------------------------------------------------
#define T1B 3840
#define T2B 6528

__global__ __launch_bounds__(256) void logit_tails(
    const short* __restrict__ P1c, const short* __restrict__ WlT1,
    const float* __restrict__ bl1, float* __restrict__ ps1,
    const short* __restrict__ P2c, const short* __restrict__ WlT2,
    const float* __restrict__ bl2, float* __restrict__ ps2,
    const int* __restrict__ counts) {
  int b = blockIdx.x;
  const short* A; const short* BT; const float* bias; float* ps;
  int K, Ncols, nsplit, rb, cs, cnt;
  if (b < T1B) {
    const int xcd = b & 7, j = b >> 3;
    rb = j / 30; cs = xcd * 30 + j % 30;
    if (cs >= 235) return;
    A = P1c; BT = WlT1; bias = bl1; ps = ps1;
    K = 256; Ncols = 30000; nsplit = 235; cnt = counts[1];
  } else {
    b -= T1B;
    const int xcd = b & 7, j = b >> 3;
    rb = j / 51; cs = xcd * 51 + j % 51;
    if (cs >= 407) return;
    A = P2c; BT = WlT2; bias = bl2; ps = ps2;
    K = 64; Ncols = 52000; nsplit = 407; cnt = counts[2];
  }
  const int r0 = rb * 128, c0 = cs * 128;
  if (r0 >= cnt) return;

  __shared__ short As[128 * 64];
  __shared__ short Bs[128 * 64];
  __shared__ float psL[2][128];
  const int tid = threadIdx.x;
  const int w = tid >> 6, lane = tid & 63;
  const int quad = lane >> 4, ln = lane & 15;
  const int wm = w >> 1, wn = w & 1;
  const int rsub = lane >> 3;
  const int kc = (lane & 7) ^ rsub;

  const short* aB[4]; const short* bB[4];
#pragma unroll
  for (int i = 0; i < 4; ++i) {
    aB[i] = A + (size_t)(r0 + w * 32 + i * 8 + rsub) * K + kc * 8;
    bB[i] = BT + (size_t)(c0 + w * 32 + i * 8 + rsub) * K + kc * 8;
  }

  f32x4 acc[4][4];
  const f32x4 zero = {0.f, 0.f, 0.f, 0.f};
#pragma unroll
  for (int i = 0; i < 4; ++i)
#pragma unroll
    for (int jj = 0; jj < 4; ++jj) acc[i][jj] = zero;
  mfma_mainloop(aB, bB, As, Bs, acc, K, w, lane);

  float bv[4];
#pragma unroll
  for (int nt = 0; nt < 4; ++nt) {
    const int cg = c0 + wn * 64 + nt * 16 + ln;
    bv[nt] = (cg < Ncols) ? bias[cg] : -1.0e30f;
  }
#pragma unroll
  for (int mt = 0; mt < 4; ++mt)
#pragma unroll
    for (int r = 0; r < 4; ++r) {
      float s = 0.f;
#pragma unroll
      for (int nt = 0; nt < 4; ++nt)
        s += __expf(acc[mt][nt][r] + bv[nt]);
#pragma unroll
      for (int off = 1; off < 16; off <<= 1) s += __shfl_xor(s, off, 64);
      if (ln == 0) psL[wn][wm * 64 + mt * 16 + quad * 4 + r] = s;
    }
  __syncthreads();
  if (tid < 128)
    ps[(size_t)(r0 + tid) * nsplit + cs] = psL[0][tid] + psL[1][tid];
}

// ---------------------------------------------------------------------------
// FINALIZE: one wave per row (unchanged).
// ---------------------------------------------------------------------------
__global__ __launch_bounds__(256) void finalize(
    const short* __restrict__ P0b, const short* __restrict__ P1c,
    const short* __restrict__ P2c,
    const short* __restrict__ WlT0, const float* __restrict__ bl0,
    const short* __restrict__ WlT1, const float* __restrict__ bl1,
    const short* __restrict__ WlT2, const float* __restrict__ bl2,
    const float* __restrict__ Wc, const float* __restrict__ bc,
    const int* __restrict__ y, const int* __restrict__ slot_of_row,
    const float* __restrict__ psh, const float* __restrict__ ps1,
    const float* __restrict__ ps2, float* __restrict__ out) {
  const int lane = threadIdx.x & 63;
  const int row = blockIdx.x * 4 + (threadIdx.x >> 6);

  float a0 = 0.f, a1 = 0.f;
  for (int k = lane; k < HID; k += 64) {
    const float p = bf2f(P0b[(size_t)row * HID + k]);
    a0 += p * Wc[2 * k];
    a1 += p * Wc[2 * k + 1];
  }
  a0 = wave_sum(a0);
  a1 = wave_sum(a1);
  const float cl0 = a0 + bc[0], cl1 = a1 + bc[1];

  float S = 0.f;
  for (int i = lane; i < 79; i += 64) S += psh[(size_t)row * 79 + i];
  S = wave_sum(S) + __expf(cl0) + __expf(cl1);
  const float lse = logf(S);

  const int yy = y[row];
  float nll;
  if (yy < 10000) {
    const short* pr = P0b + (size_t)row * 1024;
    const short* wr = WlT0 + (size_t)yy * 1024;
    float a = 0.f;
    for (int kk = lane * 4; kk < 1024; kk += 256) {
      const short4_t p = *(const short4_t*)(pr + kk);
      const short4_t wv = *(const short4_t*)(wr + kk);
      a += bf2f(p.x) * bf2f(wv.x) + bf2f(p.y) * bf2f(wv.y)
         + bf2f(p.z) * bf2f(wv.z) + bf2f(p.w) * bf2f(wv.w);
    }
    a = wave_sum(a);
    nll = -((a + bl0[yy]) - lse);
  } else if (yy < 20000) {
    const int t = yy - 10000;
    const int slot = slot_of_row[row];
    float S1 = 0.f;
    for (int i = lane; i < 235; i += 64) S1 += ps1[(size_t)slot * 235 + i];
    S1 = wave_sum(S1);
    const short* pr = P1c + (size_t)slot * 256;
    const short* wr = WlT1 + (size_t)t * 256;
    const int kk = lane * 4;
    const short4_t p = *(const short4_t*)(pr + kk);
    const short4_t wv = *(const short4_t*)(wr + kk);
    float a = bf2f(p.x) * bf2f(wv.x) + bf2f(p.y) * bf2f(wv.y)
            + bf2f(p.z) * bf2f(wv.z) + bf2f(p.w) * bf2f(wv.w);
    a = wave_sum(a);
    nll = -((cl1 - lse) + ((a + bl1[t]) - logf(S1)));
  } else {
    const int t = yy - 20000;
    const int slot = slot_of_row[row];
    float S2 = 0.f;
    for (int i = lane; i < 407; i += 64) S2 += ps2[(size_t)slot * 407 + i];
    S2 = wave_sum(S2);
    float a = 0.f;
    if (lane < 16) {
      const short* pr = P2c + (size_t)slot * 64;
      const short* wr = WlT2 + (size_t)t * 64;
      const int kk = lane * 4;
      const short4_t p = *(const short4_t*)(pr + kk);
      const short4_t wv = *(const short4_t*)(wr + kk);
      a = bf2f(p.x) * bf2f(wv.x) + bf2f(p.y) * bf2f(wv.y)
        + bf2f(p.z) * bf2f(wv.z) + bf2f(p.w) * bf2f(wv.w);
    }
    a = wave_sum(a);
    nll = -((cl0 - lse) + ((a + bl2[t]) - logf(S2)));
  }
  if (lane == 0) out[row] = nll;
}

// ---------------------------------------------------------------------------
extern "C" void kernel_launch(void* const* d_in, const int* in_sizes, int n_in,
                              void* d_out, int out_size, void* d_ws, size_t ws_size,
                              hipStream_t stream) {
  const float* x   = (const float*)d_in[0];
  const int*   y   = (const int*)d_in[1];
  const float* Wp0 = (const float*)d_in[2];
  const float* Wp1 = (const float*)d_in[3];
  const float* Wp2 = (const float*)d_in[4];
  const float* Wl0 = (const float*)d_in[5];
  const float* bl0 = (const float*)d_in[6];
  const float* Wl1 = (const float*)d_in[7];
  const float* bl1 = (const float*)d_in[8];
  const float* Wl2 = (const float*)d_in[9];
  const float* bl2 = (const float*)d_in[10];
  const float* Wc  = (const float*)d_in[11];
  const float* bc  = (const float*)d_in[12];
  float* out = (float*)d_out;

  float* fws = (float*)d_ws;
  float* psh = fws; fws += (size_t)NROWS * 79;
  float* ps1 = fws; fws += (size_t)NROWS * 235;
  float* ps2 = fws; fws += (size_t)NROWS * 407;
  int* iws = (int*)fws;
  int* counts      = iws; iws += 4;
  int* slot_of_row = iws; iws += NROWS;
  int* rows1       = iws; iws += NROWS;
  int* rows2       = iws; iws += NROWS;
  short* sp = (short*)iws;
  short* xb   = sp; sp += (size_t)NROWS * 1024;
  short* P0b  = sp; sp += (size_t)NROWS * 1024;
  short* P1c  = sp; sp += (size_t)NROWS * 256;
  short* P2c  = sp; sp += (size_t)NROWS * 64;
  short* WpT0 = sp; sp += (size_t)1024 * 1024;
  short* WpT1 = sp; sp += (size_t)256 * 1024;
  short* WpT2 = sp; sp += (size_t)128 * 1024;
  short* WlT0 = sp; sp += (size_t)10240 * 1024;
  short* WlT1 = sp; sp += (size_t)30208 * 256;
  short* WlT2 = sp; sp += (size_t)52224 * 64;

  dim3 blk(256);
  prep<<<dim3(6129), blk, 0, stream>>>(x, y, Wp0, Wp1, Wp2, Wl0, Wl1, Wl2,
                                       xb, counts, slot_of_row, rows1, rows2,
                                       WpT0, WpT1, WpT2, WlT0, WlT1, WlT2);
  proj_all<<<dim3(176), blk, 0, stream>>>(xb, WpT0, WpT1, WpT2, P0b, P1c, P2c,
                                          rows1, rows2, counts);
  logit_tails<<<dim3(T1B + T2B), blk, 0, stream>>>(
      P1c, WlT1, bl1, ps1, P2c, WlT2, bl2, ps2, counts);
  logit_head<<<dim3(320), dim3(512), 0, stream>>>(P0b, WlT0, bl0, psh);
  finalize<<<dim3(NROWS / 4), blk, 0, stream>>>(
      P0b, P1c, P2c, WlT0, bl0, WlT1, bl1, WlT2, bl2, Wc, bc, y, slot_of_row,
      psh, ps1, ps2, out);
}